// Round 1
// baseline (444.487 us; speedup 1.0000x reference)
//
#include <hip/hip_runtime.h>
#include <math.h>

// ProductManifoldPhasorBlock — fp32 correctness-first implementation.
// B=4, L=1024, D=256, N_PER=48, N_HYP=16, K=64.
// Pipeline:
//  1) gemm_big      : 5 problems (4x GELU MLP hidden layers + V projection)
//  2) gemm_small    : 4 second layers (N=48/48/32/32), tanh*scale epilogue
//  3) phasor_kernel : build (re,im) phasors for key & query
//  4) phase_a       : per-chunk sums  P[b,c,k,d] = sum_{l in chunk} k[l,k]*V[l,d]
//  5) phase_b       : in-place exclusive prefix over chunks (scan carry)
//  6) phase_c       : in-chunk sequential scan, state in VGPRs, retrieved/norm
//  7) layernorm
//  8) gemm_big      : out projection with residual-add epilogue -> d_out

#define Bn 4
#define Ln 1024
#define Dn 256
#define BLn 4096
#define KKn 64
#define LCn 32   // chunk length
#define NCn 32   // chunks per batch

// ---------------------------------------------------------------- big GEMM
// Y[M,256] = act(X[M,256] @ W[256,256]^T + bias) (+ res). Tile 128x128, 8x8/thread.
struct BigProb { const float* X; const float* W; const float* bias; const float* res; float* Y; int act; };
struct BigArgs { BigProb p[5]; };

__global__ __launch_bounds__(256) void gemm_big(BigArgs a) {
  const BigProb p = a.p[blockIdx.z];
  __shared__ float As[16][128];   // k-major
  __shared__ float Bs[16][128];
  const int tid = threadIdx.x;
  const int m0 = blockIdx.x * 128;
  const int n0 = blockIdx.y * 128;
  const int tx = tid & 15, ty = tid >> 4;
  float acc[8][8];
#pragma unroll
  for (int i = 0; i < 8; i++)
#pragma unroll
    for (int j = 0; j < 8; j++) acc[i][j] = 0.f;

  for (int k0 = 0; k0 < 256; k0 += 16) {
#pragma unroll
    for (int i = 0; i < 2; i++) {
      int idx = tid * 2 + i;          // 0..511 float4 slots
      int r = idx >> 2;               // 0..127
      int kq = (idx & 3) << 2;        // 0,4,8,12
      const float4 va = *(const float4*)(p.X + (m0 + r) * 256 + k0 + kq);
      As[kq + 0][r] = va.x; As[kq + 1][r] = va.y; As[kq + 2][r] = va.z; As[kq + 3][r] = va.w;
      const float4 vb = *(const float4*)(p.W + (n0 + r) * 256 + k0 + kq);
      Bs[kq + 0][r] = vb.x; Bs[kq + 1][r] = vb.y; Bs[kq + 2][r] = vb.z; Bs[kq + 3][r] = vb.w;
    }
    __syncthreads();
#pragma unroll
    for (int k = 0; k < 16; k++) {
      float a8[8], b8[8];
      *(float4*)&a8[0] = *(const float4*)&As[k][ty * 8];
      *(float4*)&a8[4] = *(const float4*)&As[k][ty * 8 + 4];
      *(float4*)&b8[0] = *(const float4*)&Bs[k][tx * 8];
      *(float4*)&b8[4] = *(const float4*)&Bs[k][tx * 8 + 4];
#pragma unroll
      for (int i = 0; i < 8; i++)
#pragma unroll
        for (int j = 0; j < 8; j++) acc[i][j] += a8[i] * b8[j];
    }
    __syncthreads();
  }
#pragma unroll
  for (int i = 0; i < 8; i++) {
    int m = m0 + ty * 8 + i;
#pragma unroll
    for (int j = 0; j < 8; j++) {
      int n = n0 + tx * 8 + j;
      float o = acc[i][j] + p.bias[n];
      if (p.act == 1) o = 0.5f * o * (1.0f + erff(o * 0.70710678118654752440f));
      if (p.res) o += p.res[m * 256 + n];
      p.Y[m * 256 + n] = o;
    }
  }
}

// ------------------------------------------------------------- small-N GEMM
// Y[M,N] = tanh(X[M,256] @ W[N,256]^T + bias) * scale, N in {48,32}.
struct SmProb { const float* X; const float* W; const float* bias; float* Y; int N; float scale; };
struct SmArgs { SmProb p[4]; };

__global__ __launch_bounds__(256) void gemm_small(SmArgs a) {
  const SmProb p = a.p[blockIdx.y];
  __shared__ float Xs[32][264];   // pad 264: 16B-aligned rows, bank-spread
  const int tid = threadIdx.x;
  const int m0 = blockIdx.x * 32;
#pragma unroll
  for (int i = 0; i < 8; i++) {
    int idx = tid + i * 256;       // 0..2047 float4 slots (32 rows x 64)
    int r = idx >> 6;
    int kq = (idx & 63) << 2;
    *(float4*)&Xs[r][kq] = *(const float4*)(p.X + (m0 + r) * 256 + kq);
  }
  __syncthreads();
  const int r = tid >> 3;
  const int nn = tid & 7;
  const int nch = p.N >> 3;
  for (int cn = 0; cn < nch; cn++) {
    int n = cn * 8 + nn;
    const float* wr = p.W + n * 256;
    float acc = 0.f;
#pragma unroll 16
    for (int kq = 0; kq < 64; kq++) {
      float4 xv = *(const float4*)&Xs[r][kq << 2];
      float4 wv = *(const float4*)(wr + (kq << 2));
      acc += xv.x * wv.x + xv.y * wv.y + xv.z * wv.z + xv.w * wv.w;
    }
    p.Y[(m0 + r) * p.N + n] = tanhf(acc + p.bias[n]) * p.scale;
  }
}

// ----------------------------------------------------------------- phasors
__global__ void phasor_kernel(const float* kp, const float* kh,
                              const float* qp, const float* qh,
                              float* kre, float* kim, float* qre, float* qim) {
  int gid = blockIdx.x * 256 + threadIdx.x;   // BL*64
  int row = gid >> 6;
  int k = gid & 63;
  const float *per, *hyp; float *ore, *oim;
  if (blockIdx.y == 0) { per = kp; hyp = kh; ore = kre; oim = kim; }
  else                 { per = qp; hyp = qh; ore = qre; oim = qim; }
  float re, im;
  if (k < 48) {
    float ang = per[row * 48 + k];          // already tanh*pi
    re = cosf(ang); im = sinf(ang);
  } else {
    int j = k - 48;
    float av = hyp[row * 32 + 2 * j];       // already tanh*0.9
    float bv = hyp[row * 32 + 2 * j + 1];
    float rr = sqrtf(av * av + bv * bv);
    if (rr > 0.f) { float inv = (1.0f - rr) / rr; re = av * inv; im = bv * inv; }
    else          { re = 1.0f; im = 0.0f; }  // atan2(0,0)=0, amp=1
  }
  ore[gid] = re;
  oim[gid] = im;
}

// ------------------------------------------------------------ scan phase A
// P[b,c,k,d] = sum_{l in chunk c} key[l,k] * V[l,d]   (complex key, real V)
__global__ __launch_bounds__(64) void phase_a(const float* kre, const float* kim,
                                              const float* V, float* Pre, float* Pim) {
  __shared__ float kk[64][2];
  const int tid = threadIdx.x;
  const int bc = blockIdx.x;          // b*NC + c
  const int b = bc >> 5;
  const int c = bc & 31;
  const int d = blockIdx.y * 64 + tid;
  float pr[64], pi[64];
#pragma unroll
  for (int k = 0; k < 64; k++) { pr[k] = 0.f; pi[k] = 0.f; }
  const int lbase = b * Ln + c * LCn;
  for (int l = 0; l < LCn; l++) {
    int lrow = lbase + l;
    kk[tid][0] = kre[lrow * 64 + tid];
    kk[tid][1] = kim[lrow * 64 + tid];
    __syncthreads();
    float v = V[lrow * 256 + d];
#pragma unroll
    for (int k = 0; k < 64; k++) {
      float2 kv = *(const float2*)&kk[k][0];
      pr[k] += kv.x * v;
      pi[k] += kv.y * v;
    }
    __syncthreads();
  }
  const int pbase = (bc * 64) * 256 + d;
#pragma unroll
  for (int k = 0; k < 64; k++) {
    Pre[pbase + k * 256] = pr[k];
    Pim[pbase + k * 256] = pi[k];
  }
}

// ------------------------------------------------------------ scan phase B
// In-place exclusive prefix over the NC chunks for each (b,k,d).
__global__ void phase_b(float* Pre, float* Pim) {
  int gid = blockIdx.x * 256 + threadIdx.x;   // B*K*D = 65536
  float* P = (blockIdx.y == 0) ? Pre : Pim;
  int b = gid >> 14;
  int kd = gid & 16383;
  int idx = b * (NCn * 64 * 256) + kd;
  float run = 0.f;
#pragma unroll 8
  for (int c = 0; c < NCn; c++) {
    float t = P[idx];
    P[idx] = run;
    run += t;
    idx += 64 * 256;
  }
}

// ------------------------------------------------------------ scan phase C
// In-chunk sequential scan: state S[k] (complex) in VGPRs, one thread per d.
__global__ __launch_bounds__(64) void phase_c(const float* kre, const float* kim,
                                              const float* qre, const float* qim,
                                              const float* V, const float* Pre, const float* Pim,
                                              float* R) {
  __shared__ float quad[64][4];   // (kre,kim,qre,qim) per k
  const int tid = threadIdx.x;
  const int bc = blockIdx.x;
  const int b = bc >> 5;
  const int c = bc & 31;
  const int d = blockIdx.y * 64 + tid;
  float sr[64], si[64];
  const int pbase = (bc * 64) * 256 + d;
#pragma unroll
  for (int k = 0; k < 64; k++) {
    sr[k] = Pre[pbase + k * 256];
    si[k] = Pim[pbase + k * 256];
  }
  const int lbase = b * Ln + c * LCn;
  for (int l = 0; l < LCn; l++) {
    int lrow = lbase + l;
    float4 q;
    q.x = kre[lrow * 64 + tid];
    q.y = kim[lrow * 64 + tid];
    q.z = qre[lrow * 64 + tid];
    q.w = qim[lrow * 64 + tid];
    *(float4*)&quad[tid][0] = q;
    __syncthreads();
    float v = V[lrow * 256 + d];
    float a0 = 0.f, a1 = 0.f, a2 = 0.f, a3 = 0.f;
#pragma unroll
    for (int k = 0; k < 64; k++) {
      float4 kv = *(const float4*)&quad[k][0];
      sr[k] += kv.x * v;
      si[k] += kv.y * v;
      if ((k & 1) == 0) { a0 += kv.z * sr[k]; a2 += kv.w * si[k]; }
      else              { a1 += kv.z * sr[k]; a3 += kv.w * si[k]; }
    }
    int pos = c * LCn + l + 1;               // 1-based position
    R[lrow * 256 + d] = (a0 + a1 + a2 + a3) * rsqrtf((float)pos * 64.0f);
    __syncthreads();
  }
}

// ---------------------------------------------------------------- layernorm
__global__ __launch_bounds__(256) void layernorm(const float* R, const float* g,
                                                 const float* bta, float* Y) {
  __shared__ float red[8];
  const int row = blockIdx.x;
  const int tid = threadIdx.x;
  float v = R[row * 256 + tid];
  float s = v, sq = v * v;
#pragma unroll
  for (int off = 32; off >= 1; off >>= 1) {
    s  += __shfl_down(s, off, 64);
    sq += __shfl_down(sq, off, 64);
  }
  int wave = tid >> 6;
  if ((tid & 63) == 0) { red[wave * 2] = s; red[wave * 2 + 1] = sq; }
  __syncthreads();
  float ts = 0.f, tsq = 0.f;
#pragma unroll
  for (int w = 0; w < 4; w++) { ts += red[w * 2]; tsq += red[w * 2 + 1]; }
  float mean = ts * (1.0f / 256.0f);
  float var = tsq * (1.0f / 256.0f) - mean * mean;
  var = fmaxf(var, 0.f);
  float rstd = rsqrtf(var + 1e-5f);
  Y[row * 256 + tid] = (v - mean) * rstd * g[tid] + bta[tid];
}

// ------------------------------------------------------------------- launch
extern "C" void kernel_launch(void* const* d_in, const int* in_sizes, int n_in,
                              void* d_out, int out_size, void* d_ws, size_t ws_size,
                              hipStream_t stream) {
  const float* x     = (const float*)d_in[0];
  const float* kp_w1 = (const float*)d_in[1];
  const float* kp_b1 = (const float*)d_in[2];
  const float* kp_w2 = (const float*)d_in[3];
  const float* kp_b2 = (const float*)d_in[4];
  const float* qp_w1 = (const float*)d_in[5];
  const float* qp_b1 = (const float*)d_in[6];
  const float* qp_w2 = (const float*)d_in[7];
  const float* qp_b2 = (const float*)d_in[8];
  const float* kh_w1 = (const float*)d_in[9];
  const float* kh_b1 = (const float*)d_in[10];
  const float* kh_w2 = (const float*)d_in[11];
  const float* kh_b2 = (const float*)d_in[12];
  const float* qh_w1 = (const float*)d_in[13];
  const float* qh_b1 = (const float*)d_in[14];
  const float* qh_w2 = (const float*)d_in[15];
  const float* qh_b2 = (const float*)d_in[16];
  const float* v_w   = (const float*)d_in[17];
  const float* v_b   = (const float*)d_in[18];
  const float* ln_g  = (const float*)d_in[19];
  const float* ln_b  = (const float*)d_in[20];
  const float* out_w = (const float*)d_in[21];
  const float* out_b = (const float*)d_in[22];

  float* ws = (float*)d_ws;
  // workspace layout (floats). P_re/P_im alias the h region (h dead by phase A).
  const size_t HBUF = (size_t)BLn * 256;          // 1,048,576
  float* h0  = ws;                                 // 4 hidden buffers
  float* h1  = ws + HBUF;
  float* h2  = ws + 2 * HBUF;
  float* h3  = ws + 3 * HBUF;
  float* Pre = ws;                                 // alias h0/h1 (2,097,152 floats)
  float* Pim = ws + 2 * HBUF;                      // alias h2/h3
  float* V   = ws + 4 * HBUF;
  float* kp  = V + HBUF;                           // BL*48
  float* qp  = kp + (size_t)BLn * 48;
  float* kh  = qp + (size_t)BLn * 48;              // BL*32
  float* qh  = kh + (size_t)BLn * 32;
  float* kre = qh + (size_t)BLn * 32;              // BL*64 each
  float* kim = kre + (size_t)BLn * 64;
  float* qre = kim + (size_t)BLn * 64;
  float* qim = qre + (size_t)BLn * 64;
  float* r   = qim + (size_t)BLn * 64;             // BL*256
  float* rln = r + HBUF;                           // BL*256

  // 1) first layers + V projection (5 problems)
  BigArgs ba;
  ba.p[0] = { x, kp_w1, kp_b1, nullptr, h0, 1 };
  ba.p[1] = { x, qp_w1, qp_b1, nullptr, h1, 1 };
  ba.p[2] = { x, kh_w1, kh_b1, nullptr, h2, 1 };
  ba.p[3] = { x, qh_w1, qh_b1, nullptr, h3, 1 };
  ba.p[4] = { x, v_w,   v_b,   nullptr, V,  0 };
  gemm_big<<<dim3(32, 2, 5), 256, 0, stream>>>(ba);

  // 2) second layers: tanh * scale
  const float PI_F = 3.14159265358979323846f;
  SmArgs sa;
  sa.p[0] = { h0, kp_w2, kp_b2, kp, 48, PI_F };
  sa.p[1] = { h1, qp_w2, qp_b2, qp, 48, PI_F };
  sa.p[2] = { h2, kh_w2, kh_b2, kh, 32, 0.9f };
  sa.p[3] = { h3, qh_w2, qh_b2, qh, 32, 0.9f };
  gemm_small<<<dim3(128, 4), 256, 0, stream>>>(sa);

  // 3) phasors
  phasor_kernel<<<dim3(1024, 2), 256, 0, stream>>>(kp, kh, qp, qh, kre, kim, qre, qim);

  // 4-6) chunked scan
  phase_a<<<dim3(Bn * NCn, 4), 64, 0, stream>>>(kre, kim, V, Pre, Pim);
  phase_b<<<dim3(256, 2), 256, 0, stream>>>(Pre, Pim);
  phase_c<<<dim3(Bn * NCn, 4), 64, 0, stream>>>(kre, kim, qre, qim, V, Pre, Pim, r);

  // 7) layernorm
  layernorm<<<BLn, 256, 0, stream>>>(r, ln_g, ln_b, rln);

  // 8) out projection + residual
  BigArgs fa;
  fa.p[0] = { rln, out_w, out_b, x, (float*)d_out, 0 };
  fa.p[1] = fa.p[0]; fa.p[2] = fa.p[0]; fa.p[3] = fa.p[0]; fa.p[4] = fa.p[0];
  gemm_big<<<dim3(32, 2, 1), 256, 0, stream>>>(fa);
}

// Round 2
// 197.605 us; speedup vs baseline: 2.2494x; 2.2494x over previous
//
#include <hip/hip_runtime.h>
#include <math.h>

// ProductManifoldPhasorBlock — R2: bf16-MFMA GEMMs + restructured scan.
// B=4, L=1024, D=256, K=64. NC=64 chunks of LC=16.

#define Bn 4
#define Ln 1024
#define BLn 4096
#define NCn 64
#define LCn 16

typedef __attribute__((ext_vector_type(8))) short bf16x8;
typedef __attribute__((ext_vector_type(4))) float f32x4;

__device__ inline float bf2f(ushort u) {
  union { uint u32; float f; } x; x.u32 = ((uint)u) << 16; return x.f;
}
__device__ inline ushort f2bf(float f) {
  union { float f; uint u; } x; x.f = f;
  uint r = x.u + 0x7fffu + ((x.u >> 16) & 1u);
  return (ushort)(r >> 16);
}

// ------------------------------------------------------------------- cast
// All segments are [rows][256] fp32 -> bf16; rows >= nreal write 0 (padding).
struct CastArgs { const float* src[11]; ushort* dst[11]; int rows[11]; int nreal[11]; };

__global__ void cast_bf16(CastArgs a) {
  const int s = blockIdx.y;
  const float* src = a.src[s];
  ushort* dst = a.dst[s];
  const int n = a.rows[s] * 256;
  const int nreal = a.nreal[s];
  for (int i = blockIdx.x * blockDim.x + threadIdx.x; i < n; i += gridDim.x * blockDim.x) {
    int row = i >> 8;
    float v = (row < nreal) ? src[row * 256 + (i & 255)] : 0.f;
    dst[i] = f2bf(v);
  }
}

// ------------------------------------------------------------- MFMA GEMM
// Y[M,N] = act(Xbf16[M,256] @ Wbf16[N,256]^T + bias), 64x64 tile, 4 waves,
// each wave 32x32 via 2x2 mfma_f32_16x16x32_bf16 frags. LDS stride 40 bf16
// (80B = 20 banks: 8 consecutive rows cover all 32 banks -> 2-way = free).
// act: 0 = none->f32, 1 = GELU->bf16, 2 = tanh*scale->f32, 3 = +res->f32.
struct MProb { const ushort* X; const ushort* W; const float* bias; const float* res;
               void* Y; int act; int Nreal; float scale; };
struct MArgs { MProb p[5]; };

__global__ __launch_bounds__(256) void gemm_mfma(MArgs args) {
  const MProb p = args.p[blockIdx.z];
  const int ldY = gridDim.y * 64;
  __shared__ ushort As[64 * 40];
  __shared__ ushort Bs[64 * 40];
  const int tid = threadIdx.x;
  const int m0 = blockIdx.x * 64, n0 = blockIdx.y * 64;
  const int lane = tid & 63, wave = tid >> 6;
  const int wr = wave >> 1, wc = wave & 1;
  const int fr = lane & 15, quad = lane >> 4;
  f32x4 acc[2][2];
#pragma unroll
  for (int i = 0; i < 2; i++)
#pragma unroll
    for (int j = 0; j < 2; j++) acc[i][j] = (f32x4){0.f, 0.f, 0.f, 0.f};

  const int srow = tid >> 2, sch = (tid & 3) * 8;
  for (int k0 = 0; k0 < 256; k0 += 32) {
    uint4 va = *(const uint4*)(p.X + (m0 + srow) * 256 + k0 + sch);
    uint4 vb = *(const uint4*)(p.W + (n0 + srow) * 256 + k0 + sch);
    *(uint4*)&As[srow * 40 + sch] = va;
    *(uint4*)&Bs[srow * 40 + sch] = vb;
    __syncthreads();
    bf16x8 a0 = *(const bf16x8*)&As[(wr * 32 + fr) * 40 + quad * 8];
    bf16x8 a1 = *(const bf16x8*)&As[(wr * 32 + 16 + fr) * 40 + quad * 8];
    bf16x8 b0 = *(const bf16x8*)&Bs[(wc * 32 + fr) * 40 + quad * 8];
    bf16x8 b1 = *(const bf16x8*)&Bs[(wc * 32 + 16 + fr) * 40 + quad * 8];
    acc[0][0] = __builtin_amdgcn_mfma_f32_16x16x32_bf16(a0, b0, acc[0][0], 0, 0, 0);
    acc[0][1] = __builtin_amdgcn_mfma_f32_16x16x32_bf16(a0, b1, acc[0][1], 0, 0, 0);
    acc[1][0] = __builtin_amdgcn_mfma_f32_16x16x32_bf16(a1, b0, acc[1][0], 0, 0, 0);
    acc[1][1] = __builtin_amdgcn_mfma_f32_16x16x32_bf16(a1, b1, acc[1][1], 0, 0, 0);
    __syncthreads();
  }
  // epilogue: C/D layout col = lane&15, row = (lane>>4)*4 + reg
#pragma unroll
  for (int i = 0; i < 2; i++)
#pragma unroll
    for (int j = 0; j < 2; j++) {
      int col = n0 + wc * 32 + j * 16 + fr;
      float bv = (col < p.Nreal) ? p.bias[col] : 0.f;
#pragma unroll
      for (int r = 0; r < 4; r++) {
        int rowg = m0 + wr * 32 + i * 16 + quad * 4 + r;
        float o = acc[i][j][r] + bv;
        if (p.act == 1) o = 0.5f * o * (1.0f + erff(o * 0.70710678118654752f));
        else if (p.act == 2) o = tanhf(o) * p.scale;
        else if (p.act == 3) o += p.res[rowg * 256 + col];
        if (p.act == 1) ((ushort*)p.Y)[rowg * ldY + col] = f2bf(o);
        else ((float*)p.Y)[rowg * ldY + col] = o;
      }
    }
}

// ----------------------------------------------------------------- phasors
// Writes kq4[row,k] = (kre,kim,qre,qim) and kk2[row,k] = (kre,kim).
__global__ void phasor_kernel(const float* kp, const float* kh,
                              const float* qp, const float* qh,
                              float4* kq4, float2* kk2) {
  int gid = blockIdx.x * 256 + threadIdx.x;   // BL*64
  int row = gid >> 6, k = gid & 63;
  float kre, kim, qre, qim;
  if (k < 48) {
    float ka = kp[row * 64 + k], qa = qp[row * 64 + k];
    kre = cosf(ka); kim = sinf(ka);
    qre = cosf(qa); qim = sinf(qa);
  } else {
    int j2 = (k - 48) * 2;
    float av = kh[row * 64 + j2], bv = kh[row * 64 + j2 + 1];
    float rr = sqrtf(av * av + bv * bv);
    if (rr > 0.f) { float inv = (1.0f - rr) / rr; kre = av * inv; kim = bv * inv; }
    else          { kre = 1.0f; kim = 0.0f; }
    av = qh[row * 64 + j2]; bv = qh[row * 64 + j2 + 1];
    rr = sqrtf(av * av + bv * bv);
    if (rr > 0.f) { float inv = (1.0f - rr) / rr; qre = av * inv; qim = bv * inv; }
    else          { qre = 1.0f; qim = 0.0f; }
  }
  kq4[gid] = make_float4(kre, kim, qre, qim);
  kk2[gid] = make_float2(kre, kim);
}

// ------------------------------------------------------------ scan phase A
// P[bc,k,d] = sum_{l in chunk} key[l,k]*V[l,d]; grid (B*NC, ksplit=2), 256 thr.
__global__ __launch_bounds__(256) void phase_a(const float2* kk2, const float* V,
                                               ushort* Pre, ushort* Pim) {
  __shared__ float2 ks[2][32];
  const int tid = threadIdx.x;
  const int bc = blockIdx.x;
  const int koff = blockIdx.y * 32;
  const int b = bc >> 6, c = bc & 63;
  float pr[32], pi[32];
#pragma unroll
  for (int k = 0; k < 32; k++) { pr[k] = 0.f; pi[k] = 0.f; }
  const int lbase = b * Ln + c * LCn;
  for (int l = 0; l < LCn; l++) {
    int lrow = lbase + l;
    if (tid < 32) ks[l & 1][tid] = kk2[lrow * 64 + koff + tid];
    __syncthreads();
    float v = V[lrow * 256 + tid];
    const float2* kk = ks[l & 1];
#pragma unroll
    for (int k = 0; k < 32; k++) {
      float2 kv = kk[k];
      pr[k] += kv.x * v;
      pi[k] += kv.y * v;
    }
  }
  const int pbase = (bc * 64 + koff) * 256 + tid;
#pragma unroll
  for (int k = 0; k < 32; k++) {
    Pre[pbase + k * 256] = f2bf(pr[k]);
    Pim[pbase + k * 256] = f2bf(pi[k]);
  }
}

// ------------------------------------------------------------ scan phase B
// Exclusive prefix over NC chunks, in place, fp32 carry / bf16 storage.
__global__ void phase_b(ushort* Pre, ushort* Pim) {
  int gid = blockIdx.x * 256 + threadIdx.x;   // B*K*D = 65536
  ushort* P = blockIdx.y ? Pim : Pre;
  int b = gid >> 14, kd = gid & 16383;
  size_t idx = (size_t)b * (NCn * 16384) + kd;
  float run = 0.f;
  for (int c = 0; c < NCn; c++) {
    float t = bf2f(P[idx]);
    P[idx] = f2bf(run);
    run += t;
    idx += 16384;
  }
}

// ------------------------------------------------------------ scan phase C
// grid (B*NC, ksplit=2), 128 threads; each thread owns 2 d-columns (d, d+128)
// and 32 complex states in VGPRs. Writes k-half partials to r0/r1.
__global__ __launch_bounds__(128) void phase_c(const float4* kq4, const float* V,
                                               const ushort* Pre, const ushort* Pim,
                                               float* r0, float* r1) {
  __shared__ float4 qs[2][32];
  const int tid = threadIdx.x;          // = d0; d1 = d0+128
  const int bc = blockIdx.x;
  const int koff = blockIdx.y * 32;
  float* Rh = blockIdx.y ? r1 : r0;
  const int b = bc >> 6, c = bc & 63;
  float sr0[32], si0[32], sr1[32], si1[32];
  const int pbase = (bc * 64 + koff) * 256 + tid;
#pragma unroll
  for (int k = 0; k < 32; k++) {
    sr0[k] = bf2f(Pre[pbase + k * 256]);
    si0[k] = bf2f(Pim[pbase + k * 256]);
    sr1[k] = bf2f(Pre[pbase + k * 256 + 128]);
    si1[k] = bf2f(Pim[pbase + k * 256 + 128]);
  }
  const int lbase = b * Ln + c * LCn;
  for (int l = 0; l < LCn; l++) {
    int lrow = lbase + l;
    if (tid < 32) qs[l & 1][tid] = kq4[lrow * 64 + koff + tid];
    __syncthreads();
    float v0 = V[lrow * 256 + tid];
    float v1 = V[lrow * 256 + 128 + tid];
    float a0 = 0.f, a1 = 0.f, a2 = 0.f, a3 = 0.f;
    const float4* qq = qs[l & 1];
#pragma unroll
    for (int k = 0; k < 32; k++) {
      float4 kv = qq[k];
      sr0[k] += kv.x * v0; si0[k] += kv.y * v0;
      sr1[k] += kv.x * v1; si1[k] += kv.y * v1;
      a0 += kv.z * sr0[k]; a1 += kv.w * si0[k];
      a2 += kv.z * sr1[k]; a3 += kv.w * si1[k];
    }
    float nrm = rsqrtf((float)(c * LCn + l + 1) * 64.0f);
    Rh[lrow * 256 + tid] = (a0 + a1) * nrm;
    Rh[lrow * 256 + 128 + tid] = (a2 + a3) * nrm;
  }
}

// ---------------------------------------------------------------- layernorm
__global__ __launch_bounds__(256) void layernorm(const float* r0, const float* r1,
                                                 const float* g, const float* bta,
                                                 ushort* Y) {
  __shared__ float red[8];
  const int row = blockIdx.x;
  const int tid = threadIdx.x;
  float v = r0[row * 256 + tid] + r1[row * 256 + tid];
  float s = v, sq = v * v;
#pragma unroll
  for (int off = 32; off >= 1; off >>= 1) {
    s  += __shfl_down(s, off, 64);
    sq += __shfl_down(sq, off, 64);
  }
  int wave = tid >> 6;
  if ((tid & 63) == 0) { red[wave * 2] = s; red[wave * 2 + 1] = sq; }
  __syncthreads();
  float ts = 0.f, tsq = 0.f;
#pragma unroll
  for (int w = 0; w < 4; w++) { ts += red[w * 2]; tsq += red[w * 2 + 1]; }
  float mean = ts * (1.0f / 256.0f);
  float var = fmaxf(tsq * (1.0f / 256.0f) - mean * mean, 0.f);
  float rstd = rsqrtf(var + 1e-5f);
  Y[row * 256 + tid] = f2bf((v - mean) * rstd * g[tid] + bta[tid]);
}

// ------------------------------------------------------------------- launch
extern "C" void kernel_launch(void* const* d_in, const int* in_sizes, int n_in,
                              void* d_out, int out_size, void* d_ws, size_t ws_size,
                              hipStream_t stream) {
  const float* x     = (const float*)d_in[0];
  const float* kp_w1 = (const float*)d_in[1];
  const float* kp_b1 = (const float*)d_in[2];
  const float* kp_w2 = (const float*)d_in[3];
  const float* kp_b2 = (const float*)d_in[4];
  const float* qp_w1 = (const float*)d_in[5];
  const float* qp_b1 = (const float*)d_in[6];
  const float* qp_w2 = (const float*)d_in[7];
  const float* qp_b2 = (const float*)d_in[8];
  const float* kh_w1 = (const float*)d_in[9];
  const float* kh_b1 = (const float*)d_in[10];
  const float* kh_w2 = (const float*)d_in[11];
  const float* kh_b2 = (const float*)d_in[12];
  const float* qh_w1 = (const float*)d_in[13];
  const float* qh_b1 = (const float*)d_in[14];
  const float* qh_w2 = (const float*)d_in[15];
  const float* qh_b2 = (const float*)d_in[16];
  const float* v_w   = (const float*)d_in[17];
  const float* v_b   = (const float*)d_in[18];
  const float* ln_g  = (const float*)d_in[19];
  const float* ln_b  = (const float*)d_in[20];
  const float* out_w = (const float*)d_in[21];
  const float* out_b = (const float*)d_in[22];

  char* ws = (char*)d_ws;
  const size_t MiB = 1024 * 1024;
  // P region [0,16MiB) aliases h (dead after gemm2) and kp..qh (dead after phasor)
  ushort* Pre = (ushort*)(ws + 0);                 // 8 MiB
  ushort* Pim = (ushort*)(ws + 8 * MiB);           // 8 MiB
  ushort* h0  = (ushort*)(ws + 0);                 // 2 MiB each
  ushort* h1  = (ushort*)(ws + 2 * MiB);
  ushort* h2  = (ushort*)(ws + 4 * MiB);
  ushort* h3  = (ushort*)(ws + 6 * MiB);
  float*  kp  = (float*)(ws + 8 * MiB);            // 1 MiB each (stride 64)
  float*  qp  = (float*)(ws + 9 * MiB);
  float*  kh  = (float*)(ws + 10 * MiB);
  float*  qh  = (float*)(ws + 11 * MiB);
  ushort* xb  = (ushort*)(ws + 16 * MiB);          // 2 MiB
  ushort* wb1[6];
  for (int i = 0; i < 6; i++) wb1[i] = (ushort*)(ws + 18 * MiB + (size_t)i * 128 * 1024);
  ushort* wb2[4];
  for (int i = 0; i < 4; i++) wb2[i] = (ushort*)(ws + 18 * MiB + 768 * 1024 + (size_t)i * 32 * 1024);
  float*  V   = (float*)(ws + 19 * MiB);           // 4 MiB
  float4* kq4 = (float4*)(ws + 23 * MiB);          // 4 MiB
  float2* kk2 = (float2*)(ws + 27 * MiB);          // 2 MiB
  float*  r0  = (float*)(ws + 29 * MiB);           // 4 MiB
  float*  r1  = (float*)(ws + 33 * MiB);           // 4 MiB
  ushort* rln = (ushort*)(ws + 37 * MiB);          // 2 MiB

  // 0) casts: x + 6 big weights + 4 padded second-layer weights
  CastArgs ca;
  const float* srcs[11] = { x, kp_w1, qp_w1, kh_w1, qh_w1, v_w, out_w,
                            kp_w2, qp_w2, kh_w2, qh_w2 };
  ushort* dsts[11] = { xb, wb1[0], wb1[1], wb1[2], wb1[3], wb1[4], wb1[5],
                       wb2[0], wb2[1], wb2[2], wb2[3] };
  int rows[11]  = { 4096, 256, 256, 256, 256, 256, 256, 64, 64, 64, 64 };
  int nreal[11] = { 4096, 256, 256, 256, 256, 256, 256, 48, 48, 32, 32 };
  for (int i = 0; i < 11; i++) { ca.src[i] = srcs[i]; ca.dst[i] = dsts[i]; ca.rows[i] = rows[i]; ca.nreal[i] = nreal[i]; }
  cast_bf16<<<dim3(256, 11), 256, 0, stream>>>(ca);

  const float PI_F = 3.14159265358979323846f;
  // 1) first layers + V projection
  MArgs g1;
  g1.p[0] = { xb, wb1[0], kp_b1, nullptr, h0, 1, 256, 0.f };
  g1.p[1] = { xb, wb1[1], qp_b1, nullptr, h1, 1, 256, 0.f };
  g1.p[2] = { xb, wb1[2], kh_b1, nullptr, h2, 1, 256, 0.f };
  g1.p[3] = { xb, wb1[3], qh_b1, nullptr, h3, 1, 256, 0.f };
  g1.p[4] = { xb, wb1[4], v_b,   nullptr, V,  0, 256, 0.f };
  gemm_mfma<<<dim3(64, 4, 5), 256, 0, stream>>>(g1);

  // 2) second layers (N=64 padded), tanh*scale epilogue
  MArgs g2;
  g2.p[0] = { h0, wb2[0], kp_b2, nullptr, kp, 2, 48, PI_F };
  g2.p[1] = { h1, wb2[1], qp_b2, nullptr, qp, 2, 48, PI_F };
  g2.p[2] = { h2, wb2[2], kh_b2, nullptr, kh, 2, 32, 0.9f };
  g2.p[3] = { h3, wb2[3], qh_b2, nullptr, qh, 2, 32, 0.9f };
  g2.p[4] = g2.p[0];
  gemm_mfma<<<dim3(64, 1, 4), 256, 0, stream>>>(g2);

  // 3) phasors
  phasor_kernel<<<dim3(1024), 256, 0, stream>>>(kp, kh, qp, qh, kq4, kk2);

  // 4-6) chunked scan
  phase_a<<<dim3(Bn * NCn, 2), 256, 0, stream>>>(kk2, V, Pre, Pim);
  phase_b<<<dim3(256, 2), 256, 0, stream>>>(Pre, Pim);
  phase_c<<<dim3(Bn * NCn, 2), 128, 0, stream>>>(kq4, V, Pre, Pim, r0, r1);

  // 7) layernorm -> bf16
  layernorm<<<dim3(BLn), 256, 0, stream>>>(r0, r1, ln_g, ln_b, rln);

  // 8) out projection + residual
  MArgs g3;
  g3.p[0] = { rln, wb1[5], out_b, x, d_out, 3, 256, 0.f };
  g3.p[1] = g3.p[0]; g3.p[2] = g3.p[0]; g3.p[3] = g3.p[0]; g3.p[4] = g3.p[0];
  gemm_mfma<<<dim3(64, 4, 1), 256, 0, stream>>>(g3);
}

// Round 4
// 177.280 us; speedup vs baseline: 2.5073x; 1.1147x over previous
//
#include <hip/hip_runtime.h>
#include <math.h>

// ProductManifoldPhasorBlock — R4: R3 all-MFMA formulation, fixed phasor_t
// transpose loop bound (was it<32 -> OOB LDS reads + cross-batch PhiKT
// corruption -> NaN; correct slot count is 128 k2-rows x 32 l-pairs = 4096).
// retrieved = tril(PhiQ @ PhiK^T) @ V  via chunked (chunk=64) linear attention:
//   kv_chunk: P^T[b,c][d][k2] = VT_c @ PhiKT_c^T          (MFMA, direct-global)
//   prefix  : exclusive scan over chunks, fp32 carry -> bf16 SpreB
//   retrieve: O = PhiQ@SpreB^T + tril(PhiQ@PhiK^T)@V      (MFMA, S via LDS)
// B=4, L=1024, D=256, K=64 (k2=128 interleaved re/im), 16 chunks/batch.

#define Bn 4
#define Ln 1024
#define BLn 4096

typedef __attribute__((ext_vector_type(8))) short bf16x8;
typedef __attribute__((ext_vector_type(4))) float f32x4;

__device__ inline float bf2f(ushort u) {
  union { uint u32; float f; } x; x.u32 = ((uint)u) << 16; return x.f;
}
__device__ inline ushort f2bf(float f) {
  union { float f; uint u; } x; x.f = f;
  uint r = x.u + 0x7fffu + ((x.u >> 16) & 1u);
  return (ushort)(r >> 16);
}

// ------------------------------------------------------------------- cast
struct CastArgs { const float* src[11]; ushort* dst[11]; int rows[11]; int nreal[11]; };

__global__ void cast_bf16(CastArgs a) {
  const int s = blockIdx.y;
  const float* src = a.src[s];
  ushort* dst = a.dst[s];
  const int n = a.rows[s] * 256;
  const int nreal = a.nreal[s];
  for (int i = blockIdx.x * blockDim.x + threadIdx.x; i < n; i += gridDim.x * blockDim.x) {
    int row = i >> 8;
    float v = (row < nreal) ? src[row * 256 + (i & 255)] : 0.f;
    dst[i] = f2bf(v);
  }
}

// ------------------------------------------------------------- MFMA GEMM
// act: 0 none->f32, 1 GELU->bf16, 2 tanh*scale->f32, 3 +res->f32, 4 bf16 transposed (VT)
struct MProb { const ushort* X; const ushort* W; const float* bias; const float* res;
               void* Y; int act; int Nreal; float scale; int ldY; };
struct MArgs { MProb p[5]; };

__global__ __launch_bounds__(256) void gemm_mfma(MArgs args) {
  const MProb p = args.p[blockIdx.z];
  __shared__ ushort As[64 * 40];
  __shared__ ushort Bs[64 * 40];
  const int tid = threadIdx.x;
  const int m0 = blockIdx.x * 64, n0 = blockIdx.y * 64;
  const int lane = tid & 63, wave = tid >> 6;
  const int wr = wave >> 1, wc = wave & 1;
  const int fr = lane & 15, quad = lane >> 4;
  f32x4 acc[2][2];
#pragma unroll
  for (int i = 0; i < 2; i++)
#pragma unroll
    for (int j = 0; j < 2; j++) acc[i][j] = (f32x4){0.f, 0.f, 0.f, 0.f};

  const int srow = tid >> 2, sch = (tid & 3) * 8;
  for (int k0 = 0; k0 < 256; k0 += 32) {
    uint4 va = *(const uint4*)(p.X + (size_t)(m0 + srow) * 256 + k0 + sch);
    uint4 vb = *(const uint4*)(p.W + (size_t)(n0 + srow) * 256 + k0 + sch);
    *(uint4*)&As[srow * 40 + sch] = va;
    *(uint4*)&Bs[srow * 40 + sch] = vb;
    __syncthreads();
    bf16x8 a0 = *(const bf16x8*)&As[(wr * 32 + fr) * 40 + quad * 8];
    bf16x8 a1 = *(const bf16x8*)&As[(wr * 32 + 16 + fr) * 40 + quad * 8];
    bf16x8 b0 = *(const bf16x8*)&Bs[(wc * 32 + fr) * 40 + quad * 8];
    bf16x8 b1 = *(const bf16x8*)&Bs[(wc * 32 + 16 + fr) * 40 + quad * 8];
    acc[0][0] = __builtin_amdgcn_mfma_f32_16x16x32_bf16(a0, b0, acc[0][0], 0, 0, 0);
    acc[0][1] = __builtin_amdgcn_mfma_f32_16x16x32_bf16(a0, b1, acc[0][1], 0, 0, 0);
    acc[1][0] = __builtin_amdgcn_mfma_f32_16x16x32_bf16(a1, b0, acc[1][0], 0, 0, 0);
    acc[1][1] = __builtin_amdgcn_mfma_f32_16x16x32_bf16(a1, b1, acc[1][1], 0, 0, 0);
    __syncthreads();
  }
#pragma unroll
  for (int i = 0; i < 2; i++)
#pragma unroll
    for (int j = 0; j < 2; j++) {
      int col = n0 + wc * 32 + j * 16 + fr;
      float bv = (col < p.Nreal) ? p.bias[col] : 0.f;
      if (p.act == 4) {
        ushort4 st;
        int rowg0 = m0 + wr * 32 + i * 16 + quad * 4;
        st.x = f2bf(acc[i][j][0] + bv);
        st.y = f2bf(acc[i][j][1] + bv);
        st.z = f2bf(acc[i][j][2] + bv);
        st.w = f2bf(acc[i][j][3] + bv);
        *(ushort4*)((ushort*)p.Y + (size_t)col * 4096 + rowg0) = st;
      } else {
#pragma unroll
        for (int r = 0; r < 4; r++) {
          int rowg = m0 + wr * 32 + i * 16 + quad * 4 + r;
          float o = acc[i][j][r] + bv;
          if (p.act == 1) o = 0.5f * o * (1.0f + erff(o * 0.70710678118654752f));
          else if (p.act == 2) o = tanhf(o) * p.scale;
          else if (p.act == 3) o += p.res[(size_t)rowg * 256 + col];
          if (p.act == 1) ((ushort*)p.Y)[(size_t)rowg * p.ldY + col] = f2bf(o);
          else ((float*)p.Y)[(size_t)rowg * p.ldY + col] = o;
        }
      }
    }
}

// ----------------------------------------------------------------- phasors
// Emit PhiQ/PhiK [BL][128] bf16 (uint-packed pairs) and PhiKT [B][128][1024] bf16.
__global__ __launch_bounds__(256) void phasor_t(const float* kp, const float* qp,
                                                const float* kh, const float* qh,
                                                uint* PhiQ, uint* PhiK, uint* PhiKT) {
  __shared__ ushort LK[64][130];
  const int t = threadIdx.x;
  const int row0 = blockIdx.x * 64;
  const int b = row0 >> 10;
  const int lb0 = row0 & 1023;
#pragma unroll
  for (int it = 0; it < 16; it++) {
    int idx = t + it * 256;            // 64 rows x 64 k
    int k = idx & 63, rl = idx >> 6;
    int row = row0 + rl;
    float kre, kim, qre, qim;
    if (k < 48) {
      float ka = kp[row * 64 + k], qa = qp[row * 64 + k];
      __sincosf(ka, &kim, &kre);
      __sincosf(qa, &qim, &qre);
    } else {
      int j2 = (k - 48) * 2;
      float av = kh[row * 64 + j2], bv = kh[row * 64 + j2 + 1];
      float rr = sqrtf(av * av + bv * bv);
      if (rr > 0.f) { float inv = (1.0f - rr) / rr; kre = av * inv; kim = bv * inv; }
      else          { kre = 1.0f; kim = 0.0f; }
      av = qh[row * 64 + j2]; bv = qh[row * 64 + j2 + 1];
      rr = sqrtf(av * av + bv * bv);
      if (rr > 0.f) { float inv = (1.0f - rr) / rr; qre = av * inv; qim = bv * inv; }
      else          { qre = 1.0f; qim = 0.0f; }
    }
    uint pk = (uint)f2bf(kre) | ((uint)f2bf(kim) << 16);
    uint pq = (uint)f2bf(qre) | ((uint)f2bf(qim) << 16);
    PhiK[(size_t)row * 64 + k] = pk;
    PhiQ[(size_t)row * 64 + k] = pq;
    *(uint*)&LK[rl][2 * k] = pk;
  }
  __syncthreads();
#pragma unroll
  for (int it = 0; it < 16; it++) {     // FIX: 128 k2-rows x 32 l-pairs = 4096
    int idx = t + it * 256;
    int k2 = idx >> 5, lp = idx & 31;
    uint v = (uint)LK[lp * 2][k2] | ((uint)LK[lp * 2 + 1][k2] << 16);
    PhiKT[(size_t)b * 65536 + k2 * 512 + (lb0 >> 1) + lp] = v;
  }
}

// -------------------------------------------------------------- kv chunks
// P[b,c][d 256][k2 128] = sum_{l in chunk} V[l][d] * PhiK[l][k2]; grid (64, 2).
__global__ __launch_bounds__(256) void kv_chunk(const ushort* VT, const ushort* PhiKT,
                                                float* P) {
  const int bc = blockIdx.x;
  const int b = bc >> 4, c = bc & 15;
  const int d0 = blockIdx.y * 128;
  const int tid = threadIdx.x, lane = tid & 63, wave = tid >> 6;
  const int wr = wave >> 1, wc = wave & 1;
  const int fr = lane & 15, quad = lane >> 4;
  const int colb = b * 1024 + c * 64;
  f32x4 acc[4][4];
#pragma unroll
  for (int i = 0; i < 4; i++)
#pragma unroll
    for (int j = 0; j < 4; j++) acc[i][j] = (f32x4){0.f, 0.f, 0.f, 0.f};
#pragma unroll
  for (int kk = 0; kk < 2; kk++) {
    bf16x8 a[4], bb[4];
#pragma unroll
    for (int i = 0; i < 4; i++)
      a[i] = *(const bf16x8*)(VT + (size_t)(d0 + wr * 64 + i * 16 + fr) * 4096 + colb + kk * 32 + quad * 8);
#pragma unroll
    for (int j = 0; j < 4; j++)
      bb[j] = *(const bf16x8*)(PhiKT + (size_t)b * 131072 + (size_t)(wc * 64 + j * 16 + fr) * 1024 + c * 64 + kk * 32 + quad * 8);
#pragma unroll
    for (int i = 0; i < 4; i++)
#pragma unroll
      for (int j = 0; j < 4; j++)
        acc[i][j] = __builtin_amdgcn_mfma_f32_16x16x32_bf16(a[i], bb[j], acc[i][j], 0, 0, 0);
  }
#pragma unroll
  for (int i = 0; i < 4; i++)
#pragma unroll
    for (int j = 0; j < 4; j++)
#pragma unroll
      for (int r = 0; r < 4; r++) {
        int d = d0 + wr * 64 + i * 16 + quad * 4 + r;
        int k2 = wc * 64 + j * 16 + fr;
        P[((size_t)bc * 256 + d) * 128 + k2] = acc[i][j][r];
      }
}

// ----------------------------------------------------------------- prefix
// Exclusive prefix over 16 chunks; fp32 carry, bf16 output.
__global__ void prefix_scan(const float* P, ushort* SpreB) {
  int gid = blockIdx.x * 256 + threadIdx.x;   // 4*256*128 = 131072
  int b = gid >> 15, dk = gid & 32767;
  size_t idx = (size_t)b * 16 * 32768 + dk;
  float run = 0.f;
#pragma unroll 4
  for (int c = 0; c < 16; c++) {
    SpreB[idx] = f2bf(run);
    run += P[idx];
    idx += 32768;
  }
}

// --------------------------------------------------------------- retrieve
// O = PhiQ @ SpreB^T + tril(PhiQ @ PhiK^T) @ V, scaled; grid (64, 2), 4 waves.
__global__ __launch_bounds__(256) void retrieve(const ushort* PhiQ, const ushort* PhiK,
                                                const ushort* VT, const ushort* SpreB,
                                                float* R) {
  __shared__ ushort Sl[64 * 72];
  const int bc = blockIdx.x;
  const int b = bc >> 4, c = bc & 15;
  const int d0 = blockIdx.y * 128;
  const int tid = threadIdx.x, lane = tid & 63, wy = tid >> 6;
  const int fr = lane & 15, quad = lane >> 4;
  const int g0 = b * 1024 + c * 64;
  // cache all A fragments (PhiQ rows)
  bf16x8 a[4][4];
#pragma unroll
  for (int i = 0; i < 4; i++)
#pragma unroll
    for (int kk = 0; kk < 4; kk++)
      a[i][kk] = *(const bf16x8*)(PhiQ + (size_t)(g0 + i * 16 + fr) * 128 + kk * 32 + quad * 8);

  f32x4 acc[4][2];
#pragma unroll
  for (int i = 0; i < 4; i++)
#pragma unroll
    for (int j = 0; j < 2; j++) acc[i][j] = (f32x4){0.f, 0.f, 0.f, 0.f};

  // inter-chunk: PhiQ @ SpreB^T
#pragma unroll
  for (int kk = 0; kk < 4; kk++) {
    bf16x8 bb[2];
#pragma unroll
    for (int j = 0; j < 2; j++)
      bb[j] = *(const bf16x8*)(SpreB + ((size_t)bc * 256 + d0 + wy * 32 + j * 16 + fr) * 128 + kk * 32 + quad * 8);
#pragma unroll
    for (int i = 0; i < 4; i++)
#pragma unroll
      for (int j = 0; j < 2; j++)
        acc[i][j] = __builtin_amdgcn_mfma_f32_16x16x32_bf16(a[i][kk], bb[j], acc[i][j], 0, 0, 0);
  }

  // intra-chunk scores: wave wy computes 16-col strip of S (64x64)
  f32x4 sacc[4];
#pragma unroll
  for (int i = 0; i < 4; i++) sacc[i] = (f32x4){0.f, 0.f, 0.f, 0.f};
#pragma unroll
  for (int kk = 0; kk < 4; kk++) {
    bf16x8 bs = *(const bf16x8*)(PhiK + (size_t)(g0 + wy * 16 + fr) * 128 + kk * 32 + quad * 8);
#pragma unroll
    for (int i = 0; i < 4; i++)
      sacc[i] = __builtin_amdgcn_mfma_f32_16x16x32_bf16(a[i][kk], bs, sacc[i], 0, 0, 0);
  }
#pragma unroll
  for (int i = 0; i < 4; i++)
#pragma unroll
    for (int r = 0; r < 4; r++) {
      int row = i * 16 + quad * 4 + r;
      int col = wy * 16 + fr;
      Sl[row * 72 + col] = (col <= row) ? f2bf(sacc[i][r]) : (ushort)0;
    }
  __syncthreads();

  // intra-chunk PV: tril(S) @ V
#pragma unroll
  for (int kk = 0; kk < 2; kk++) {
    bf16x8 as[4], bv[2];
#pragma unroll
    for (int i = 0; i < 4; i++)
      as[i] = *(const bf16x8*)&Sl[(i * 16 + fr) * 72 + kk * 32 + quad * 8];
#pragma unroll
    for (int j = 0; j < 2; j++)
      bv[j] = *(const bf16x8*)(VT + (size_t)(d0 + wy * 32 + j * 16 + fr) * 4096 + g0 + kk * 32 + quad * 8);
#pragma unroll
    for (int i = 0; i < 4; i++)
#pragma unroll
      for (int j = 0; j < 2; j++)
        acc[i][j] = __builtin_amdgcn_mfma_f32_16x16x32_bf16(as[i], bv[j], acc[i][j], 0, 0, 0);
  }

#pragma unroll
  for (int i = 0; i < 4; i++)
#pragma unroll
    for (int j = 0; j < 2; j++)
#pragma unroll
      for (int r = 0; r < 4; r++) {
        int row = i * 16 + quad * 4 + r;
        int d = d0 + wy * 32 + j * 16 + fr;
        float scale = rsqrtf((float)((c * 64 + row + 1) * 64));
        R[(size_t)(g0 + row) * 256 + d] = acc[i][j][r] * scale;
      }
}

// ---------------------------------------------------------------- layernorm
__global__ __launch_bounds__(256) void layernorm(const float* Rin, const float* g,
                                                 const float* bta, ushort* Y) {
  __shared__ float red[8];
  const int row = blockIdx.x;
  const int tid = threadIdx.x;
  float v = Rin[(size_t)row * 256 + tid];
  float s = v, sq = v * v;
#pragma unroll
  for (int off = 32; off >= 1; off >>= 1) {
    s  += __shfl_down(s, off, 64);
    sq += __shfl_down(sq, off, 64);
  }
  int wave = tid >> 6;
  if ((tid & 63) == 0) { red[wave * 2] = s; red[wave * 2 + 1] = sq; }
  __syncthreads();
  float ts = 0.f, tsq = 0.f;
#pragma unroll
  for (int w = 0; w < 4; w++) { ts += red[w * 2]; tsq += red[w * 2 + 1]; }
  float mean = ts * (1.0f / 256.0f);
  float var = fmaxf(tsq * (1.0f / 256.0f) - mean * mean, 0.f);
  float rstd = rsqrtf(var + 1e-5f);
  Y[(size_t)row * 256 + tid] = f2bf((v - mean) * rstd * g[tid] + bta[tid]);
}

// ------------------------------------------------------------------- launch
extern "C" void kernel_launch(void* const* d_in, const int* in_sizes, int n_in,
                              void* d_out, int out_size, void* d_ws, size_t ws_size,
                              hipStream_t stream) {
  const float* x     = (const float*)d_in[0];
  const float* kp_w1 = (const float*)d_in[1];
  const float* kp_b1 = (const float*)d_in[2];
  const float* kp_w2 = (const float*)d_in[3];
  const float* kp_b2 = (const float*)d_in[4];
  const float* qp_w1 = (const float*)d_in[5];
  const float* qp_b1 = (const float*)d_in[6];
  const float* qp_w2 = (const float*)d_in[7];
  const float* qp_b2 = (const float*)d_in[8];
  const float* kh_w1 = (const float*)d_in[9];
  const float* kh_b1 = (const float*)d_in[10];
  const float* kh_w2 = (const float*)d_in[11];
  const float* kh_b2 = (const float*)d_in[12];
  const float* qh_w1 = (const float*)d_in[13];
  const float* qh_b1 = (const float*)d_in[14];
  const float* qh_w2 = (const float*)d_in[15];
  const float* qh_b2 = (const float*)d_in[16];
  const float* v_w   = (const float*)d_in[17];
  const float* v_b   = (const float*)d_in[18];
  const float* ln_g  = (const float*)d_in[19];
  const float* ln_b  = (const float*)d_in[20];
  const float* out_w = (const float*)d_in[21];
  const float* out_b = (const float*)d_in[22];

  char* ws = (char*)d_ws;
  const size_t MiB = 1024 * 1024;
  ushort* xb   = (ushort*)(ws + 0);                  // 2 MiB
  ushort* wb1[6];
  for (int i = 0; i < 6; i++) wb1[i] = (ushort*)(ws + 2 * MiB + (size_t)i * 256 * 1024);
  ushort* wb2[4];
  for (int i = 0; i < 4; i++) wb2[i] = (ushort*)(ws + 3 * MiB + 512 * 1024 + (size_t)i * 64 * 1024);
  ushort* h0   = (ushort*)(ws + 4 * MiB);            // 2 MiB each
  ushort* h1   = (ushort*)(ws + 6 * MiB);
  ushort* h2   = (ushort*)(ws + 8 * MiB);
  ushort* h3   = (ushort*)(ws + 10 * MiB);
  ushort* VT   = (ushort*)(ws + 12 * MiB);           // [256][4096] bf16, 2 MiB
  float*  kp   = (float*)(ws + 14 * MiB);            // [4096][64] fp32, 1 MiB each
  float*  qp   = (float*)(ws + 15 * MiB);
  float*  kh   = (float*)(ws + 16 * MiB);
  float*  qh   = (float*)(ws + 17 * MiB);
  uint*   PhiQ = (uint*)(ws + 18 * MiB);             // [4096][64] uint, 1 MiB
  uint*   PhiK = (uint*)(ws + 19 * MiB);             // 1 MiB
  uint*   PhiKT= (uint*)(ws + 20 * MiB);             // [4][128][512] uint, 1 MiB
  ushort* SpreB= (ushort*)(ws + 21 * MiB);           // [64][256][128] bf16, 4 MiB
  float*  P    = (float*)(ws + 25 * MiB);            // [64][256][128] fp32, 8 MiB
  float*  r    = (float*)(ws + 33 * MiB);            // 4 MiB
  ushort* rln  = (ushort*)(ws + 37 * MiB);           // 2 MiB

  // 0) casts
  CastArgs ca;
  const float* srcs[11] = { x, kp_w1, qp_w1, kh_w1, qh_w1, v_w, out_w,
                            kp_w2, qp_w2, kh_w2, qh_w2 };
  ushort* dsts[11] = { xb, wb1[0], wb1[1], wb1[2], wb1[3], wb1[4], wb1[5],
                       wb2[0], wb2[1], wb2[2], wb2[3] };
  int rows[11]  = { 4096, 256, 256, 256, 256, 256, 256, 64, 64, 64, 64 };
  int nreal[11] = { 4096, 256, 256, 256, 256, 256, 256, 48, 48, 32, 32 };
  for (int i = 0; i < 11; i++) { ca.src[i] = srcs[i]; ca.dst[i] = dsts[i]; ca.rows[i] = rows[i]; ca.nreal[i] = nreal[i]; }
  cast_bf16<<<dim3(256, 11), 256, 0, stream>>>(ca);

  const float PI_F = 3.14159265358979323846f;
  // 1) first layers (GELU->bf16) + V projection (bf16 transposed -> VT)
  MArgs g1;
  g1.p[0] = { xb, wb1[0], kp_b1, nullptr, h0, 1, 256, 0.f, 256 };
  g1.p[1] = { xb, wb1[1], qp_b1, nullptr, h1, 1, 256, 0.f, 256 };
  g1.p[2] = { xb, wb1[2], kh_b1, nullptr, h2, 1, 256, 0.f, 256 };
  g1.p[3] = { xb, wb1[3], qh_b1, nullptr, h3, 1, 256, 0.f, 256 };
  g1.p[4] = { xb, wb1[4], v_b,   nullptr, VT, 4, 256, 0.f, 0 };
  gemm_mfma<<<dim3(64, 4, 5), 256, 0, stream>>>(g1);

  // 2) second layers (N=64 padded), tanh*scale -> angles fp32
  MArgs g2;
  g2.p[0] = { h0, wb2[0], kp_b2, nullptr, kp, 2, 48, PI_F, 64 };
  g2.p[1] = { h1, wb2[1], qp_b2, nullptr, qp, 2, 48, PI_F, 64 };
  g2.p[2] = { h2, wb2[2], kh_b2, nullptr, kh, 2, 32, 0.9f, 64 };
  g2.p[3] = { h3, wb2[3], qh_b2, nullptr, qh, 2, 32, 0.9f, 64 };
  g2.p[4] = g2.p[0];
  gemm_mfma<<<dim3(64, 1, 4), 256, 0, stream>>>(g2);

  // 3) phasors -> PhiQ, PhiK, PhiKT (bf16)
  phasor_t<<<dim3(64), 256, 0, stream>>>(kp, qp, kh, qh, PhiQ, PhiK, PhiKT);

  // 4) per-chunk KV sums (MFMA)
  kv_chunk<<<dim3(64, 2), 256, 0, stream>>>(VT, (const ushort*)PhiKT, P);

  // 5) exclusive prefix over chunks -> bf16
  prefix_scan<<<dim3(512), 256, 0, stream>>>(P, SpreB);

  // 6) retrieve: inter + masked intra (MFMA)
  retrieve<<<dim3(64, 2), 256, 0, stream>>>((const ushort*)PhiQ, (const ushort*)PhiK,
                                            VT, SpreB, r);

  // 7) layernorm -> bf16
  layernorm<<<dim3(BLn), 256, 0, stream>>>(r, ln_g, ln_b, rln);

  // 8) out projection + residual
  MArgs g3;
  g3.p[0] = { rln, wb1[5], out_b, x, d_out, 3, 256, 0.f, 256 };
  g3.p[1] = g3.p[0]; g3.p[2] = g3.p[0]; g3.p[3] = g3.p[0]; g3.p[4] = g3.p[0];
  gemm_mfma<<<dim3(64, 4, 1), 256, 0, stream>>>(g3);
}